// Round 1
// baseline (3298.368 us; speedup 1.0000x reference)
//
#include <hip/hip_runtime.h>
#include <math.h>

#define NB   16
#define NP   4096
#define NC   64
#define NS   1024
#define NK   32
#define NH1  64
#define NH2  64
#define NOUT 128
#define NCIN 67

// ---------------------------------------------------------------------------
// FPS: one block per cloud, 512 threads, 8 points/thread in registers.
// Bit-exact non-FMA distance math; argmax with first-index tie-break.
// ---------------------------------------------------------------------------
__global__ __launch_bounds__(512) void fps_kernel(const float* __restrict__ pos,
                                                  float* __restrict__ pos_q,
                                                  float* __restrict__ batch_q) {
  const int b = blockIdx.x;
  const int tid = threadIdx.x;
  const float* pb = pos + (size_t)b * NP * 3;

  __shared__ float lx[NP], ly[NP], lz[NP];
  __shared__ float s_rv[8];
  __shared__ int   s_rp[8];
  __shared__ int   s_far;

  float px[8], py[8], pz[8], dist[8];
#pragma unroll
  for (int i = 0; i < 8; ++i) {
    int p = i * 512 + tid;
    float xx = pb[p * 3 + 0];
    float yy = pb[p * 3 + 1];
    float zz = pb[p * 3 + 2];
    px[i] = xx; py[i] = yy; pz[i] = zz;
    lx[p] = xx; ly[p] = yy; lz[p] = zz;
    dist[i] = __builtin_inff();
  }
  __syncthreads();

  float fx = lx[0], fy = ly[0], fz = lz[0];

  for (int s = 0; s < NS; ++s) {
    if (tid == 0) {
      size_t o = (size_t)(b * NS + s);
      pos_q[o * 3 + 0] = fx;
      pos_q[o * 3 + 1] = fy;
      pos_q[o * 3 + 2] = fz;
      batch_q[o] = (float)b;
    }
    float bv = -1.0f; int bp = 0;
#pragma unroll
    for (int i = 0; i < 8; ++i) {
      int p = i * 512 + tid;
      float dx = __fsub_rn(px[i], fx);
      float dy = __fsub_rn(py[i], fy);
      float dz = __fsub_rn(pz[i], fz);
      float d = __fadd_rn(__fadd_rn(__fmul_rn(dx, dx), __fmul_rn(dy, dy)),
                          __fmul_rn(dz, dz));
      d = fminf(dist[i], d);
      dist[i] = d;
      if (d > bv) { bv = d; bp = p; }   // ascending p => first-index kept on ties
    }
#pragma unroll
    for (int m = 1; m < 64; m <<= 1) {
      float ov = __shfl_xor(bv, m, 64);
      int   op = __shfl_xor(bp, m, 64);
      if (ov > bv || (ov == bv && op < bp)) { bv = ov; bp = op; }
    }
    if ((tid & 63) == 0) { s_rv[tid >> 6] = bv; s_rp[tid >> 6] = bp; }
    __syncthreads();
    if (tid == 0) {
      float v = s_rv[0]; int p0 = s_rp[0];
#pragma unroll
      for (int w = 1; w < 8; ++w) {
        float vw = s_rv[w]; int pw = s_rp[w];
        if (vw > v || (vw == v && pw < p0)) { v = vw; p0 = pw; }
      }
      s_far = p0;
    }
    __syncthreads();
    int far = s_far;
    fx = lx[far]; fy = ly[far]; fz = lz[far];
  }
}

// ---------------------------------------------------------------------------
// kNN: one wave (64 threads) per query. Distances for 4096 points in LDS
// (lane-local slots), 32 rounds of butterfly lexicographic-min + owner rescan.
// ---------------------------------------------------------------------------
__global__ __launch_bounds__(64) void knn_kernel(const float* __restrict__ pos,
                                                 const float* __restrict__ pos_q,
                                                 int* __restrict__ nbr) {
  __shared__ float sd[NP];
  const int q = blockIdx.x;
  const int b = q >> 10;   // q / NS
  const int lane = threadIdx.x;
  const float* pb = pos + (size_t)b * NP * 3;
  const float qx = pos_q[q * 3 + 0];
  const float qy = pos_q[q * 3 + 1];
  const float qz = pos_q[q * 3 + 2];

  float bv = __builtin_inff(); int bp = NP;
#pragma unroll 8
  for (int i = 0; i < 64; ++i) {
    int p = i * 64 + lane;
    float dx = __fsub_rn(pb[p * 3 + 0], qx);
    float dy = __fsub_rn(pb[p * 3 + 1], qy);
    float dz = __fsub_rn(pb[p * 3 + 2], qz);
    float d = __fadd_rn(__fadd_rn(__fmul_rn(dx, dx), __fmul_rn(dy, dy)),
                        __fmul_rn(dz, dz));
    sd[p] = d;
    if (d < bv) { bv = d; bp = p; }   // ascending p => lowest index on ties
  }
  // single wave; each lane touches only its own LDS slots -> no barrier needed
  for (int r = 0; r < NK; ++r) {
    float rv = bv; int rp = bp;
#pragma unroll
    for (int m = 1; m < 64; m <<= 1) {
      float ov = __shfl_xor(rv, m, 64);
      int   op = __shfl_xor(rp, m, 64);
      if (ov < rv || (ov == rv && op < rp)) { rv = ov; rp = op; }
    }
    if (lane == 0) nbr[q * NK + r] = rp;
    if ((rp & 63) == lane) {
      sd[rp] = __builtin_inff();
      bv = __builtin_inff(); bp = NP;
      for (int i = 0; i < 64; ++i) {
        int p = i * 64 + lane;
        float d = sd[p];
        if (d < bv) { bv = d; bp = p; }
      }
    }
  }
}

// ---------------------------------------------------------------------------
// PointNetConv: one block (256 threads) per query. Gather [32,67] into LDS,
// three dense layers (float4 weight loads), max over K, store 128 outputs.
// LDS strides padded (69/65/129) to avoid bank conflicts. Buffers aliased.
// ---------------------------------------------------------------------------
#define A_STRIDE 69
#define H_STRIDE 65
#define O_STRIDE 129
#define A_OFF  0
#define H1_OFF (NK * A_STRIDE)          /* 2208 */
#define H2_OFF 0                        /* alias A (dead after layer1) */
#define H3_OFF (NK * A_STRIDE)          /* alias H1 (dead after layer2) */
#define BUF_FLOATS (NK * A_STRIDE + NK * O_STRIDE)   /* 2208 + 4128 = 6336 */

__global__ __launch_bounds__(256) void conv_kernel(
    const float* __restrict__ x, const float* __restrict__ pos,
    const float* __restrict__ W1, const float* __restrict__ b1,
    const float* __restrict__ W2, const float* __restrict__ b2,
    const float* __restrict__ W3, const float* __restrict__ b3,
    const int* __restrict__ nbr, const float* __restrict__ pos_q,
    float* __restrict__ out) {
  __shared__ float buf[BUF_FLOATS];
  __shared__ int   s_nbr[NK];
  __shared__ float s_q[3];

  const int q = blockIdx.x;
  const int b = q >> 10;
  const int tid = threadIdx.x;

  if (tid < NK) s_nbr[tid] = nbr[q * NK + tid];
  if (tid >= NK && tid < NK + 3) s_q[tid - NK] = pos_q[q * 3 + (tid - NK)];
  __syncthreads();

  const float* xb = x + (size_t)b * NP * NC;
  const float* pb = pos + (size_t)b * NP * 3;

  for (int t = tid; t < NK * NC; t += 256) {
    int n = t >> 6, c = t & 63;
    buf[A_OFF + n * A_STRIDE + c] = xb[(size_t)s_nbr[n] * NC + c];
  }
  if (tid < NK * 3) {
    int n = tid / 3, d = tid - n * 3;
    buf[A_OFF + n * A_STRIDE + 64 + d] = __fsub_rn(pb[s_nbr[n] * 3 + d], s_q[d]);
  }
  __syncthreads();

  const int row = tid >> 3;
  const int cg  = tid & 7;

  // layer 1: [32,67] @ [67,64] + b1, relu
  {
    const int c0 = cg * 8;
    float acc[8];
#pragma unroll
    for (int u = 0; u < 8; ++u) acc[u] = b1[c0 + u];
    for (int j = 0; j < NCIN; ++j) {
      float a = buf[A_OFF + row * A_STRIDE + j];
      const float4 w0 = *reinterpret_cast<const float4*>(&W1[j * NH1 + c0]);
      const float4 w1 = *reinterpret_cast<const float4*>(&W1[j * NH1 + c0 + 4]);
      acc[0] = fmaf(a, w0.x, acc[0]); acc[1] = fmaf(a, w0.y, acc[1]);
      acc[2] = fmaf(a, w0.z, acc[2]); acc[3] = fmaf(a, w0.w, acc[3]);
      acc[4] = fmaf(a, w1.x, acc[4]); acc[5] = fmaf(a, w1.y, acc[5]);
      acc[6] = fmaf(a, w1.z, acc[6]); acc[7] = fmaf(a, w1.w, acc[7]);
    }
#pragma unroll
    for (int u = 0; u < 8; ++u)
      buf[H1_OFF + row * H_STRIDE + c0 + u] = fmaxf(acc[u], 0.0f);
  }
  __syncthreads();

  // layer 2: [32,64] @ [64,64] + b2, relu
  {
    const int c0 = cg * 8;
    float acc[8];
#pragma unroll
    for (int u = 0; u < 8; ++u) acc[u] = b2[c0 + u];
    for (int j = 0; j < NH1; ++j) {
      float a = buf[H1_OFF + row * H_STRIDE + j];
      const float4 w0 = *reinterpret_cast<const float4*>(&W2[j * NH2 + c0]);
      const float4 w1 = *reinterpret_cast<const float4*>(&W2[j * NH2 + c0 + 4]);
      acc[0] = fmaf(a, w0.x, acc[0]); acc[1] = fmaf(a, w0.y, acc[1]);
      acc[2] = fmaf(a, w0.z, acc[2]); acc[3] = fmaf(a, w0.w, acc[3]);
      acc[4] = fmaf(a, w1.x, acc[4]); acc[5] = fmaf(a, w1.y, acc[5]);
      acc[6] = fmaf(a, w1.z, acc[6]); acc[7] = fmaf(a, w1.w, acc[7]);
    }
#pragma unroll
    for (int u = 0; u < 8; ++u)
      buf[H2_OFF + row * H_STRIDE + c0 + u] = fmaxf(acc[u], 0.0f);
  }
  __syncthreads();

  // layer 3: [32,64] @ [64,128] + b3 (plain last)
  {
    const int c0 = cg * 16;
    float acc[16];
#pragma unroll
    for (int u = 0; u < 16; ++u) acc[u] = b3[c0 + u];
    for (int j = 0; j < NH2; ++j) {
      float a = buf[H2_OFF + row * H_STRIDE + j];
#pragma unroll
      for (int v = 0; v < 4; ++v) {
        const float4 w = *reinterpret_cast<const float4*>(&W3[j * NOUT + c0 + v * 4]);
        acc[v * 4 + 0] = fmaf(a, w.x, acc[v * 4 + 0]);
        acc[v * 4 + 1] = fmaf(a, w.y, acc[v * 4 + 1]);
        acc[v * 4 + 2] = fmaf(a, w.z, acc[v * 4 + 2]);
        acc[v * 4 + 3] = fmaf(a, w.w, acc[v * 4 + 3]);
      }
    }
#pragma unroll
    for (int u = 0; u < 16; ++u)
      buf[H3_OFF + row * O_STRIDE + c0 + u] = acc[u];
  }
  __syncthreads();

  // max over K neighbors
  if (tid < NOUT) {
    float m = -__builtin_inff();
#pragma unroll
    for (int r = 0; r < NK; ++r)
      m = fmaxf(m, buf[H3_OFF + r * O_STRIDE + tid]);
    out[(size_t)q * NOUT + tid] = m;
  }
}

extern "C" void kernel_launch(void* const* d_in, const int* in_sizes, int n_in,
                              void* d_out, int out_size, void* d_ws, size_t ws_size,
                              hipStream_t stream) {
  (void)in_sizes; (void)n_in; (void)out_size; (void)ws_size;
  const float* x   = (const float*)d_in[0];
  const float* pos = (const float*)d_in[1];
  // d_in[2] = batch (contiguous equal segments; ids derivable)
  const float* W1 = (const float*)d_in[3];
  const float* b1 = (const float*)d_in[4];
  const float* W2 = (const float*)d_in[5];
  const float* b2 = (const float*)d_in[6];
  const float* W3 = (const float*)d_in[7];
  const float* b3 = (const float*)d_in[8];

  float* out     = (float*)d_out;
  float* pos_q   = out + (size_t)NB * NS * NOUT;     // 2,097,152
  float* batch_q = pos_q + (size_t)NB * NS * 3;      // +49,152

  int* nbr = (int*)d_ws;                             // 16384*32*4 = 2 MB

  hipLaunchKernelGGL(fps_kernel, dim3(NB), dim3(512), 0, stream,
                     pos, pos_q, batch_q);
  hipLaunchKernelGGL(knn_kernel, dim3(NB * NS), dim3(64), 0, stream,
                     pos, pos_q, nbr);
  hipLaunchKernelGGL(conv_kernel, dim3(NB * NS), dim3(256), 0, stream,
                     x, pos, W1, b1, W2, b2, W3, b3, nbr, pos_q, out);
}

// Round 2
// 2532.781 us; speedup vs baseline: 1.3023x; 1.3023x over previous
//
#include <hip/hip_runtime.h>
#include <math.h>

#define NB   16
#define NP   4096
#define NC   64
#define NS   1024
#define NK   32
#define NH1  64
#define NH2  64
#define NOUT 128
#define NCIN 67

// ---------------------------------------------------------------------------
// FPS: one block per cloud, 256 threads (4 waves), 16 points/thread in
// registers. One barrier per step (double-buffered cross-wave slots).
// Packed u64 keys give argmax with first-index tie-break in the butterfly.
// Bit-exact non-FMA distance math (matches np/jnp f32).
// ---------------------------------------------------------------------------
__global__ __launch_bounds__(256) void fps_kernel(const float* __restrict__ pos,
                                                  float* __restrict__ pos_q,
                                                  float* __restrict__ batch_q) {
  const int b = blockIdx.x;
  const int tid = threadIdx.x;
  const int wave = tid >> 6;
  const float* pb = pos + (size_t)b * NP * 3;

  __shared__ float lx[NP], ly[NP], lz[NP];
  __shared__ unsigned long long s_key[2][4];
  __shared__ int s_idx[NS];

  float px[16], py[16], pz[16], dist[16];
#pragma unroll
  for (int i = 0; i < 16; ++i) {
    int p = i * 256 + tid;
    float xx = pb[p * 3 + 0];
    float yy = pb[p * 3 + 1];
    float zz = pb[p * 3 + 2];
    px[i] = xx; py[i] = yy; pz[i] = zz;
    lx[p] = xx; ly[p] = yy; lz[p] = zz;
    dist[i] = __builtin_inff();
  }
  __syncthreads();

  float fx = lx[0], fy = ly[0], fz = lz[0];
  int far = 0;

  for (int s = 0; s < NS; ++s) {
    if (tid == 0) s_idx[s] = far;

    // update dists to current sample; local best (strict > keeps lowest idx)
    float bv = -1.0f; int bp = 0;
#pragma unroll
    for (int i = 0; i < 16; ++i) {
      float dx = __fsub_rn(px[i], fx);
      float dy = __fsub_rn(py[i], fy);
      float dz = __fsub_rn(pz[i], fz);
      float d = __fadd_rn(__fadd_rn(__fmul_rn(dx, dx), __fmul_rn(dy, dy)),
                          __fmul_rn(dz, dz));
      d = fminf(dist[i], d);
      dist[i] = d;
      if (d > bv) { bv = d; bp = i * 256 + tid; }
    }

    // pack: hi = float bits of bv (bv >= 0 after first point), lo = 4095 - idx
    unsigned long long key =
        ((unsigned long long)__float_as_uint(bv) << 32) |
        (unsigned int)(NP - 1 - bp);

    // intra-wave butterfly max
#pragma unroll
    for (int m = 1; m < 64; m <<= 1) {
      unsigned long long ok = __shfl_xor(key, m, 64);
      key = (ok > key) ? ok : key;
    }
    if ((tid & 63) == 0) s_key[s & 1][wave] = key;
    __syncthreads();

    // every thread reduces the 4 wave results (same answer everywhere)
    unsigned long long k0 = s_key[s & 1][0];
    unsigned long long k1 = s_key[s & 1][1];
    unsigned long long k2 = s_key[s & 1][2];
    unsigned long long k3 = s_key[s & 1][3];
    unsigned long long ka = (k0 > k1) ? k0 : k1;
    unsigned long long kb = (k2 > k3) ? k2 : k3;
    unsigned long long km = (ka > kb) ? ka : kb;
    far = NP - 1 - (int)(unsigned int)(km & 0xFFFFFFFFull);
    fx = lx[far]; fy = ly[far]; fz = lz[far];
  }
  __syncthreads();

  // write sampled positions + batch ids (out of the serial loop)
  for (int s = tid; s < NS; s += 256) {
    int p = s_idx[s];
    size_t o = (size_t)(b * NS + s);
    pos_q[o * 3 + 0] = lx[p];
    pos_q[o * 3 + 1] = ly[p];
    pos_q[o * 3 + 2] = lz[p];
    batch_q[o] = (float)b;
  }
}

// ---------------------------------------------------------------------------
// kNN: one wave (64 threads) per query. Distances for 4096 points in LDS
// (lane-local slots), 32 rounds of butterfly lexicographic-min + owner rescan.
// ---------------------------------------------------------------------------
__global__ __launch_bounds__(64) void knn_kernel(const float* __restrict__ pos,
                                                 const float* __restrict__ pos_q,
                                                 int* __restrict__ nbr) {
  __shared__ float sd[NP];
  const int q = blockIdx.x;
  const int b = q >> 10;   // q / NS
  const int lane = threadIdx.x;
  const float* pb = pos + (size_t)b * NP * 3;
  const float qx = pos_q[q * 3 + 0];
  const float qy = pos_q[q * 3 + 1];
  const float qz = pos_q[q * 3 + 2];

  float bv = __builtin_inff(); int bp = NP;
#pragma unroll 8
  for (int i = 0; i < 64; ++i) {
    int p = i * 64 + lane;
    float dx = __fsub_rn(pb[p * 3 + 0], qx);
    float dy = __fsub_rn(pb[p * 3 + 1], qy);
    float dz = __fsub_rn(pb[p * 3 + 2], qz);
    float d = __fadd_rn(__fadd_rn(__fmul_rn(dx, dx), __fmul_rn(dy, dy)),
                        __fmul_rn(dz, dz));
    sd[p] = d;
    if (d < bv) { bv = d; bp = p; }   // ascending p => lowest index on ties
  }
  // single wave; each lane touches only its own LDS slots -> no barrier needed
  for (int r = 0; r < NK; ++r) {
    float rv = bv; int rp = bp;
#pragma unroll
    for (int m = 1; m < 64; m <<= 1) {
      float ov = __shfl_xor(rv, m, 64);
      int   op = __shfl_xor(rp, m, 64);
      if (ov < rv || (ov == rv && op < rp)) { rv = ov; rp = op; }
    }
    if (lane == 0) nbr[q * NK + r] = rp;
    if ((rp & 63) == lane) {
      sd[rp] = __builtin_inff();
      bv = __builtin_inff(); bp = NP;
      for (int i = 0; i < 64; ++i) {
        int p = i * 64 + lane;
        float d = sd[p];
        if (d < bv) { bv = d; bp = p; }
      }
    }
  }
}

// ---------------------------------------------------------------------------
// PointNetConv: one block (256 threads) per query. Gather [32,67] into LDS,
// three dense layers (float4 weight loads), max over K, store 128 outputs.
// LDS strides padded (69/65/129) to avoid bank conflicts. Buffers aliased.
// ---------------------------------------------------------------------------
#define A_STRIDE 69
#define H_STRIDE 65
#define O_STRIDE 129
#define A_OFF  0
#define H1_OFF (NK * A_STRIDE)          /* 2208 */
#define H2_OFF 0                        /* alias A (dead after layer1) */
#define H3_OFF (NK * A_STRIDE)          /* alias H1 (dead after layer2) */
#define BUF_FLOATS (NK * A_STRIDE + NK * O_STRIDE)   /* 2208 + 4128 = 6336 */

__global__ __launch_bounds__(256) void conv_kernel(
    const float* __restrict__ x, const float* __restrict__ pos,
    const float* __restrict__ W1, const float* __restrict__ b1,
    const float* __restrict__ W2, const float* __restrict__ b2,
    const float* __restrict__ W3, const float* __restrict__ b3,
    const int* __restrict__ nbr, const float* __restrict__ pos_q,
    float* __restrict__ out) {
  __shared__ float buf[BUF_FLOATS];
  __shared__ int   s_nbr[NK];
  __shared__ float s_q[3];

  const int q = blockIdx.x;
  const int b = q >> 10;
  const int tid = threadIdx.x;

  if (tid < NK) s_nbr[tid] = nbr[q * NK + tid];
  if (tid >= NK && tid < NK + 3) s_q[tid - NK] = pos_q[q * 3 + (tid - NK)];
  __syncthreads();

  const float* xb = x + (size_t)b * NP * NC;
  const float* pb = pos + (size_t)b * NP * 3;

  for (int t = tid; t < NK * NC; t += 256) {
    int n = t >> 6, c = t & 63;
    buf[A_OFF + n * A_STRIDE + c] = xb[(size_t)s_nbr[n] * NC + c];
  }
  if (tid < NK * 3) {
    int n = tid / 3, d = tid - n * 3;
    buf[A_OFF + n * A_STRIDE + 64 + d] = __fsub_rn(pb[s_nbr[n] * 3 + d], s_q[d]);
  }
  __syncthreads();

  const int row = tid >> 3;
  const int cg  = tid & 7;

  // layer 1: [32,67] @ [67,64] + b1, relu
  {
    const int c0 = cg * 8;
    float acc[8];
#pragma unroll
    for (int u = 0; u < 8; ++u) acc[u] = b1[c0 + u];
    for (int j = 0; j < NCIN; ++j) {
      float a = buf[A_OFF + row * A_STRIDE + j];
      const float4 w0 = *reinterpret_cast<const float4*>(&W1[j * NH1 + c0]);
      const float4 w1 = *reinterpret_cast<const float4*>(&W1[j * NH1 + c0 + 4]);
      acc[0] = fmaf(a, w0.x, acc[0]); acc[1] = fmaf(a, w0.y, acc[1]);
      acc[2] = fmaf(a, w0.z, acc[2]); acc[3] = fmaf(a, w0.w, acc[3]);
      acc[4] = fmaf(a, w1.x, acc[4]); acc[5] = fmaf(a, w1.y, acc[5]);
      acc[6] = fmaf(a, w1.z, acc[6]); acc[7] = fmaf(a, w1.w, acc[7]);
    }
#pragma unroll
    for (int u = 0; u < 8; ++u)
      buf[H1_OFF + row * H_STRIDE + c0 + u] = fmaxf(acc[u], 0.0f);
  }
  __syncthreads();

  // layer 2: [32,64] @ [64,64] + b2, relu
  {
    const int c0 = cg * 8;
    float acc[8];
#pragma unroll
    for (int u = 0; u < 8; ++u) acc[u] = b2[c0 + u];
    for (int j = 0; j < NH1; ++j) {
      float a = buf[H1_OFF + row * H_STRIDE + j];
      const float4 w0 = *reinterpret_cast<const float4*>(&W2[j * NH2 + c0]);
      const float4 w1 = *reinterpret_cast<const float4*>(&W2[j * NH2 + c0 + 4]);
      acc[0] = fmaf(a, w0.x, acc[0]); acc[1] = fmaf(a, w0.y, acc[1]);
      acc[2] = fmaf(a, w0.z, acc[2]); acc[3] = fmaf(a, w0.w, acc[3]);
      acc[4] = fmaf(a, w1.x, acc[4]); acc[5] = fmaf(a, w1.y, acc[5]);
      acc[6] = fmaf(a, w1.z, acc[6]); acc[7] = fmaf(a, w1.w, acc[7]);
    }
#pragma unroll
    for (int u = 0; u < 8; ++u)
      buf[H2_OFF + row * H_STRIDE + c0 + u] = fmaxf(acc[u], 0.0f);
  }
  __syncthreads();

  // layer 3: [32,64] @ [64,128] + b3 (plain last)
  {
    const int c0 = cg * 16;
    float acc[16];
#pragma unroll
    for (int u = 0; u < 16; ++u) acc[u] = b3[c0 + u];
    for (int j = 0; j < NH2; ++j) {
      float a = buf[H2_OFF + row * H_STRIDE + j];
#pragma unroll
      for (int v = 0; v < 4; ++v) {
        const float4 w = *reinterpret_cast<const float4*>(&W3[j * NOUT + c0 + v * 4]);
        acc[v * 4 + 0] = fmaf(a, w.x, acc[v * 4 + 0]);
        acc[v * 4 + 1] = fmaf(a, w.y, acc[v * 4 + 1]);
        acc[v * 4 + 2] = fmaf(a, w.z, acc[v * 4 + 2]);
        acc[v * 4 + 3] = fmaf(a, w.w, acc[v * 4 + 3]);
      }
    }
#pragma unroll
    for (int u = 0; u < 16; ++u)
      buf[H3_OFF + row * O_STRIDE + c0 + u] = acc[u];
  }
  __syncthreads();

  // max over K neighbors
  if (tid < NOUT) {
    float m = -__builtin_inff();
#pragma unroll
    for (int r = 0; r < NK; ++r)
      m = fmaxf(m, buf[H3_OFF + r * O_STRIDE + tid]);
    out[(size_t)q * NOUT + tid] = m;
  }
}

extern "C" void kernel_launch(void* const* d_in, const int* in_sizes, int n_in,
                              void* d_out, int out_size, void* d_ws, size_t ws_size,
                              hipStream_t stream) {
  (void)in_sizes; (void)n_in; (void)out_size; (void)ws_size;
  const float* x   = (const float*)d_in[0];
  const float* pos = (const float*)d_in[1];
  // d_in[2] = batch (contiguous equal segments; ids derivable)
  const float* W1 = (const float*)d_in[3];
  const float* b1 = (const float*)d_in[4];
  const float* W2 = (const float*)d_in[5];
  const float* b2 = (const float*)d_in[6];
  const float* W3 = (const float*)d_in[7];
  const float* b3 = (const float*)d_in[8];

  float* out     = (float*)d_out;
  float* pos_q   = out + (size_t)NB * NS * NOUT;     // 2,097,152
  float* batch_q = pos_q + (size_t)NB * NS * 3;      // +49,152

  int* nbr = (int*)d_ws;                             // 16384*32*4 = 2 MB

  hipLaunchKernelGGL(fps_kernel, dim3(NB), dim3(256), 0, stream,
                     pos, pos_q, batch_q);
  hipLaunchKernelGGL(knn_kernel, dim3(NB * NS), dim3(64), 0, stream,
                     pos, pos_q, nbr);
  hipLaunchKernelGGL(conv_kernel, dim3(NB * NS), dim3(256), 0, stream,
                     x, pos, W1, b1, W2, b2, W3, b3, nbr, pos_q, out);
}

// Round 3
// 1281.825 us; speedup vs baseline: 2.5732x; 1.9759x over previous
//
#include <hip/hip_runtime.h>
#include <math.h>

#define NB   16
#define NP   4096
#define NC   64
#define NS   1024
#define NK   32
#define NH1  64
#define NH2  64
#define NOUT 128
#define NCIN 67

typedef unsigned long long u64;
typedef unsigned int u32;

__device__ inline u64 umin64(u64 a, u64 b) { return a < b ? a : b; }
__device__ inline u64 umax64(u64 a, u64 b) { return a > b ? a : b; }

// round-to-nearest-even f32 -> bf16 (values finite; no NaN handling needed)
__device__ inline unsigned short f2bf(float f) {
  u32 x = __float_as_uint(f);
  return (unsigned short)((x + 0x7fffu + ((x >> 16) & 1u)) >> 16);
}
__device__ inline u32 pack2bf(float a, float b) {
  return (u32)f2bf(a) | ((u32)f2bf(b) << 16);
}
__device__ inline float bf_lo(u32 w) { return __uint_as_float(w << 16); }
__device__ inline float bf_hi(u32 w) { return __uint_as_float(w & 0xffff0000u); }

// ---------------------------------------------------------------------------
// FPS: one block per cloud, 512 threads, 8 points/thread in registers.
// One barrier per step; packed u64 keys -> argmax with first-index tie-break.
// Bit-exact non-FMA distance math.
// ---------------------------------------------------------------------------
__global__ __launch_bounds__(512) void fps_kernel(const float* __restrict__ pos,
                                                  float* __restrict__ pos_q,
                                                  float* __restrict__ batch_q) {
  const int b = blockIdx.x;
  const int tid = threadIdx.x;
  const int wave = tid >> 6;
  const float* pb = pos + (size_t)b * NP * 3;

  __shared__ float lx[NP], ly[NP], lz[NP];
  __shared__ u64 s_key[2][8];
  __shared__ int s_idx[NS];

  float px[8], py[8], pz[8], dist[8];
#pragma unroll
  for (int i = 0; i < 8; ++i) {
    int p = i * 512 + tid;
    float xx = pb[p * 3 + 0];
    float yy = pb[p * 3 + 1];
    float zz = pb[p * 3 + 2];
    px[i] = xx; py[i] = yy; pz[i] = zz;
    lx[p] = xx; ly[p] = yy; lz[p] = zz;
    dist[i] = __builtin_inff();
  }
  __syncthreads();

  float fx = lx[0], fy = ly[0], fz = lz[0];
  int far = 0;

  for (int s = 0; s < NS; ++s) {
    if (tid == 0) s_idx[s] = far;

    float bv = -1.0f; int bp = 0;
#pragma unroll
    for (int i = 0; i < 8; ++i) {
      float dx = __fsub_rn(px[i], fx);
      float dy = __fsub_rn(py[i], fy);
      float dz = __fsub_rn(pz[i], fz);
      float d = __fadd_rn(__fadd_rn(__fmul_rn(dx, dx), __fmul_rn(dy, dy)),
                          __fmul_rn(dz, dz));
      d = fminf(dist[i], d);
      dist[i] = d;
      if (d > bv) { bv = d; bp = i * 512 + tid; }
    }

    u64 key = ((u64)__float_as_uint(bv) << 32) | (u32)(NP - 1 - bp);
#pragma unroll
    for (int m = 1; m < 64; m <<= 1) {
      u64 ok = __shfl_xor(key, m, 64);
      key = (ok > key) ? ok : key;
    }
    if ((tid & 63) == 0) s_key[s & 1][wave] = key;
    __syncthreads();

    u64 km = s_key[s & 1][0];
#pragma unroll
    for (int w = 1; w < 8; ++w) {
      u64 kw = s_key[s & 1][w];
      km = (kw > km) ? kw : km;
    }
    far = NP - 1 - (int)(u32)(km & 0xFFFFFFFFull);
    fx = lx[far]; fy = ly[far]; fz = lz[far];
  }
  __syncthreads();

  for (int s = tid; s < NS; s += 512) {
    int p = s_idx[s];
    size_t o = (size_t)(b * NS + s);
    pos_q[o * 3 + 0] = lx[p];
    pos_q[o * 3 + 1] = ly[p];
    pos_q[o * 3 + 2] = lz[p];
    batch_q[o] = (float)b;
  }
}

// ---------------------------------------------------------------------------
// kNN: one wave per query, ZERO LDS. Per-lane sorted top-4 buffer of packed
// (d2bits<<32 | idx) keys; 32 rounds of butterfly-min + owner pop; rare
// refill recomputes distances (excluding extracted via per-lane bitmask).
// ---------------------------------------------------------------------------
__global__ __launch_bounds__(64) void knn_kernel(const float* __restrict__ pos,
                                                 const float* __restrict__ pos_q,
                                                 int* __restrict__ nbr) {
  const u64 KMAX = ~0ull;
  const int q = blockIdx.x;
  const int b = q >> 10;
  const int lane = threadIdx.x;
  const float* pb = pos + (size_t)b * NP * 3;
  const float qx = pos_q[q * 3 + 0];
  const float qy = pos_q[q * 3 + 1];
  const float qz = pos_q[q * 3 + 2];

  u64 b0 = KMAX, b1 = KMAX, b2 = KMAX, b3 = KMAX;
#pragma unroll 4
  for (int i = 0; i < 64; ++i) {
    int p = i * 64 + lane;
    float dx = __fsub_rn(pb[p * 3 + 0], qx);
    float dy = __fsub_rn(pb[p * 3 + 1], qy);
    float dz = __fsub_rn(pb[p * 3 + 2], qz);
    float d = __fadd_rn(__fadd_rn(__fmul_rn(dx, dx), __fmul_rn(dy, dy)),
                        __fmul_rn(dz, dz));
    u64 k = ((u64)__float_as_uint(d) << 32) | (u32)p;
    u64 m0 = umax64(b0, k); b0 = umin64(b0, k);
    u64 m1 = umax64(b1, m0); b1 = umin64(b1, m0);
    u64 m2 = umax64(b2, m1); b2 = umin64(b2, m1);
    b3 = umin64(b3, m2);
  }

  u64 exmask = 0ull;
  for (int r = 0; r < NK; ++r) {
    u64 kmin = b0;
#pragma unroll
    for (int m = 1; m < 64; m <<= 1) {
      u64 o = __shfl_xor(kmin, m, 64);
      kmin = umin64(kmin, o);
    }
    u32 p = (u32)kmin;
    if (lane == 0) nbr[q * NK + r] = (int)p;
    if ((p & 63u) == (u32)lane) {
      b0 = b1; b1 = b2; b2 = b3; b3 = KMAX;
      exmask |= 1ull << (p >> 6);
      if (b0 == KMAX) {
        // refill: rescan my 64 points, excluding extracted ones
        for (int i = 0; i < 64; ++i) {
          if ((exmask >> i) & 1ull) continue;
          int pp = i * 64 + lane;
          float dx = __fsub_rn(pb[pp * 3 + 0], qx);
          float dy = __fsub_rn(pb[pp * 3 + 1], qy);
          float dz = __fsub_rn(pb[pp * 3 + 2], qz);
          float d = __fadd_rn(__fadd_rn(__fmul_rn(dx, dx), __fmul_rn(dy, dy)),
                              __fmul_rn(dz, dz));
          u64 k = ((u64)__float_as_uint(d) << 32) | (u32)pp;
          u64 m0 = umax64(b0, k); b0 = umin64(b0, k);
          u64 m1 = umax64(b1, m0); b1 = umin64(b1, m0);
          u64 m2 = umax64(b2, m1); b2 = umin64(b2, m1);
          b3 = umin64(b3, m2);
        }
      }
    }
  }
}

// ---------------------------------------------------------------------------
// PointNetConv: 4 queries/block (one per wave), 256 threads. Activations in
// LDS as bf16 (stride 72 u16 = 144B, 16B-aligned for b128 ops); weights
// streamed from global/L1 with 4 rows x 8(16) cols per thread (acc regs force
// ILP; weight-load instrs /4 vs 1-query layout). Max-aggr in registers.
// ---------------------------------------------------------------------------
#define QB 4
#define AST 72

__global__ __launch_bounds__(256) void conv_kernel(
    const float* __restrict__ x, const float* __restrict__ pos,
    const float* __restrict__ W1, const float* __restrict__ b1,
    const float* __restrict__ W2, const float* __restrict__ b2,
    const float* __restrict__ W3, const float* __restrict__ b3,
    const int* __restrict__ nbr, const float* __restrict__ pos_q,
    float* __restrict__ out) {
  __shared__ unsigned short A[QB][32][AST];   // layer input (aliased by H2)
  __shared__ unsigned short H[QB][32][AST];   // layer1 output
  __shared__ int   s_nbr[QB][32];
  __shared__ float s_qp[QB][3];

  const int tid = threadIdx.x;
  const int wave = tid >> 6;
  const int lane = tid & 63;
  const int q = blockIdx.x * QB + wave;
  const int b = q >> 10;

  if (lane < 32) s_nbr[wave][lane] = nbr[q * NK + lane];
  else if (lane < 35) s_qp[wave][lane - 32] = pos_q[q * 3 + (lane - 32)];
  __syncthreads();

  // gather x -> A (bf16): lane covers half a neighbor row (32 channels)
  {
    const int row = lane >> 1, half = lane & 1;
    const float* src = x + ((size_t)b * NP + s_nbr[wave][row]) * NC + half * 32;
    unsigned short* dst = &A[wave][row][half * 32];
#pragma unroll
    for (int t = 0; t < 8; ++t) {
      float4 v = reinterpret_cast<const float4*>(src)[t];
      u32 lo = pack2bf(v.x, v.y);
      u32 hi = pack2bf(v.z, v.w);
      *reinterpret_cast<uint2*>(dst + t * 4) = make_uint2(lo, hi);
    }
  }
  // rel pos -> A[.][64..66], A[.][67]=0
  if (lane < 32) {
    const float* pp = pos + ((size_t)b * NP + s_nbr[wave][lane]) * 3;
    float rx = __fsub_rn(pp[0], s_qp[wave][0]);
    float ry = __fsub_rn(pp[1], s_qp[wave][1]);
    float rz = __fsub_rn(pp[2], s_qp[wave][2]);
    u32* dw = reinterpret_cast<u32*>(&A[wave][lane][64]);
    dw[0] = pack2bf(rx, ry);
    dw[1] = pack2bf(rz, 0.0f);
  }
  __syncthreads();

  const int rg = (lane >> 3) & 7;
  const int cg = lane & 7;

  float acc[4][8];

  // ----- layer 1: [32,67] @ [67,64] + b1, relu -> H -----
  {
    float4 bb0 = *reinterpret_cast<const float4*>(&b1[cg * 8]);
    float4 bb1 = *reinterpret_cast<const float4*>(&b1[cg * 8 + 4]);
#pragma unroll
    for (int u = 0; u < 4; ++u) {
      acc[u][0] = bb0.x; acc[u][1] = bb0.y; acc[u][2] = bb0.z; acc[u][3] = bb0.w;
      acc[u][4] = bb1.x; acc[u][5] = bb1.y; acc[u][6] = bb1.z; acc[u][7] = bb1.w;
    }
    for (int jb = 0; jb < 8; ++jb) {
      uint4 ar[4];
#pragma unroll
      for (int u = 0; u < 4; ++u)
        ar[u] = *reinterpret_cast<const uint4*>(&A[wave][rg + 8 * u][jb * 8]);
#pragma unroll
      for (int jj = 0; jj < 8; ++jj) {
        int j = jb * 8 + jj;
        float4 w0 = *reinterpret_cast<const float4*>(&W1[j * NH1 + cg * 8]);
        float4 w1 = *reinterpret_cast<const float4*>(&W1[j * NH1 + cg * 8 + 4]);
        float av[4];
#pragma unroll
        for (int u = 0; u < 4; ++u) {
          u32 word = reinterpret_cast<const u32*>(&ar[u])[jj >> 1];
          av[u] = (jj & 1) ? bf_hi(word) : bf_lo(word);
        }
#pragma unroll
        for (int u = 0; u < 4; ++u) {
          acc[u][0] = fmaf(av[u], w0.x, acc[u][0]);
          acc[u][1] = fmaf(av[u], w0.y, acc[u][1]);
          acc[u][2] = fmaf(av[u], w0.z, acc[u][2]);
          acc[u][3] = fmaf(av[u], w0.w, acc[u][3]);
          acc[u][4] = fmaf(av[u], w1.x, acc[u][4]);
          acc[u][5] = fmaf(av[u], w1.y, acc[u][5]);
          acc[u][6] = fmaf(av[u], w1.z, acc[u][6]);
          acc[u][7] = fmaf(av[u], w1.w, acc[u][7]);
        }
      }
    }
    // tail j = 64..66
    uint2 tw[4];
#pragma unroll
    for (int u = 0; u < 4; ++u)
      tw[u] = *reinterpret_cast<const uint2*>(&A[wave][rg + 8 * u][64]);
#pragma unroll
    for (int jj = 0; jj < 3; ++jj) {
      int j = 64 + jj;
      float4 w0 = *reinterpret_cast<const float4*>(&W1[j * NH1 + cg * 8]);
      float4 w1 = *reinterpret_cast<const float4*>(&W1[j * NH1 + cg * 8 + 4]);
      float av[4];
#pragma unroll
      for (int u = 0; u < 4; ++u)
        av[u] = (jj == 0) ? bf_lo(tw[u].x) : (jj == 1) ? bf_hi(tw[u].x) : bf_lo(tw[u].y);
#pragma unroll
      for (int u = 0; u < 4; ++u) {
        acc[u][0] = fmaf(av[u], w0.x, acc[u][0]);
        acc[u][1] = fmaf(av[u], w0.y, acc[u][1]);
        acc[u][2] = fmaf(av[u], w0.z, acc[u][2]);
        acc[u][3] = fmaf(av[u], w0.w, acc[u][3]);
        acc[u][4] = fmaf(av[u], w1.x, acc[u][4]);
        acc[u][5] = fmaf(av[u], w1.y, acc[u][5]);
        acc[u][6] = fmaf(av[u], w1.z, acc[u][6]);
        acc[u][7] = fmaf(av[u], w1.w, acc[u][7]);
      }
    }
#pragma unroll
    for (int u = 0; u < 4; ++u) {
      uint4 hw;
      hw.x = pack2bf(fmaxf(acc[u][0], 0.f), fmaxf(acc[u][1], 0.f));
      hw.y = pack2bf(fmaxf(acc[u][2], 0.f), fmaxf(acc[u][3], 0.f));
      hw.z = pack2bf(fmaxf(acc[u][4], 0.f), fmaxf(acc[u][5], 0.f));
      hw.w = pack2bf(fmaxf(acc[u][6], 0.f), fmaxf(acc[u][7], 0.f));
      *reinterpret_cast<uint4*>(&H[wave][rg + 8 * u][cg * 8]) = hw;
    }
  }
  __syncthreads();

  // ----- layer 2: [32,64] @ [64,64] + b2, relu -> A (alias) -----
  {
    float4 bb0 = *reinterpret_cast<const float4*>(&b2[cg * 8]);
    float4 bb1 = *reinterpret_cast<const float4*>(&b2[cg * 8 + 4]);
#pragma unroll
    for (int u = 0; u < 4; ++u) {
      acc[u][0] = bb0.x; acc[u][1] = bb0.y; acc[u][2] = bb0.z; acc[u][3] = bb0.w;
      acc[u][4] = bb1.x; acc[u][5] = bb1.y; acc[u][6] = bb1.z; acc[u][7] = bb1.w;
    }
    for (int jb = 0; jb < 8; ++jb) {
      uint4 ar[4];
#pragma unroll
      for (int u = 0; u < 4; ++u)
        ar[u] = *reinterpret_cast<const uint4*>(&H[wave][rg + 8 * u][jb * 8]);
#pragma unroll
      for (int jj = 0; jj < 8; ++jj) {
        int j = jb * 8 + jj;
        float4 w0 = *reinterpret_cast<const float4*>(&W2[j * NH2 + cg * 8]);
        float4 w1 = *reinterpret_cast<const float4*>(&W2[j * NH2 + cg * 8 + 4]);
        float av[4];
#pragma unroll
        for (int u = 0; u < 4; ++u) {
          u32 word = reinterpret_cast<const u32*>(&ar[u])[jj >> 1];
          av[u] = (jj & 1) ? bf_hi(word) : bf_lo(word);
        }
#pragma unroll
        for (int u = 0; u < 4; ++u) {
          acc[u][0] = fmaf(av[u], w0.x, acc[u][0]);
          acc[u][1] = fmaf(av[u], w0.y, acc[u][1]);
          acc[u][2] = fmaf(av[u], w0.z, acc[u][2]);
          acc[u][3] = fmaf(av[u], w0.w, acc[u][3]);
          acc[u][4] = fmaf(av[u], w1.x, acc[u][4]);
          acc[u][5] = fmaf(av[u], w1.y, acc[u][5]);
          acc[u][6] = fmaf(av[u], w1.z, acc[u][6]);
          acc[u][7] = fmaf(av[u], w1.w, acc[u][7]);
        }
      }
    }
#pragma unroll
    for (int u = 0; u < 4; ++u) {
      uint4 hw;
      hw.x = pack2bf(fmaxf(acc[u][0], 0.f), fmaxf(acc[u][1], 0.f));
      hw.y = pack2bf(fmaxf(acc[u][2], 0.f), fmaxf(acc[u][3], 0.f));
      hw.z = pack2bf(fmaxf(acc[u][4], 0.f), fmaxf(acc[u][5], 0.f));
      hw.w = pack2bf(fmaxf(acc[u][6], 0.f), fmaxf(acc[u][7], 0.f));
      *reinterpret_cast<uint4*>(&A[wave][rg + 8 * u][cg * 8]) = hw;
    }
  }
  __syncthreads();

  // ----- layer 3: [32,64] @ [64,128] + b3 (plain), max over rows -----
  {
    float a3[4][16];
#pragma unroll
    for (int v = 0; v < 4; ++v) {
      float4 bb = *reinterpret_cast<const float4*>(&b3[cg * 16 + v * 4]);
#pragma unroll
      for (int u = 0; u < 4; ++u) {
        a3[u][v * 4 + 0] = bb.x; a3[u][v * 4 + 1] = bb.y;
        a3[u][v * 4 + 2] = bb.z; a3[u][v * 4 + 3] = bb.w;
      }
    }
    for (int jb = 0; jb < 8; ++jb) {
      uint4 ar[4];
#pragma unroll
      for (int u = 0; u < 4; ++u)
        ar[u] = *reinterpret_cast<const uint4*>(&A[wave][rg + 8 * u][jb * 8]);
#pragma unroll
      for (int jj = 0; jj < 8; ++jj) {
        int j = jb * 8 + jj;
        float av[4];
#pragma unroll
        for (int u = 0; u < 4; ++u) {
          u32 word = reinterpret_cast<const u32*>(&ar[u])[jj >> 1];
          av[u] = (jj & 1) ? bf_hi(word) : bf_lo(word);
        }
#pragma unroll
        for (int v = 0; v < 4; ++v) {
          float4 w = *reinterpret_cast<const float4*>(&W3[j * NOUT + cg * 16 + v * 4]);
#pragma unroll
          for (int u = 0; u < 4; ++u) {
            a3[u][v * 4 + 0] = fmaf(av[u], w.x, a3[u][v * 4 + 0]);
            a3[u][v * 4 + 1] = fmaf(av[u], w.y, a3[u][v * 4 + 1]);
            a3[u][v * 4 + 2] = fmaf(av[u], w.z, a3[u][v * 4 + 2]);
            a3[u][v * 4 + 3] = fmaf(av[u], w.w, a3[u][v * 4 + 3]);
          }
        }
      }
    }
    // reduce over this thread's 4 rows, then over rg (lanes xor 8,16,32)
    float m[16];
#pragma unroll
    for (int t = 0; t < 16; ++t)
      m[t] = fmaxf(fmaxf(a3[0][t], a3[1][t]), fmaxf(a3[2][t], a3[3][t]));
#pragma unroll
    for (int off = 8; off < 64; off <<= 1) {
#pragma unroll
      for (int t = 0; t < 16; ++t)
        m[t] = fmaxf(m[t], __shfl_xor(m[t], off, 64));
    }
    if (rg == 0) {
      float* op = out + (size_t)q * NOUT + cg * 16;
#pragma unroll
      for (int v = 0; v < 4; ++v) {
        float4 o = make_float4(m[v * 4 + 0], m[v * 4 + 1], m[v * 4 + 2], m[v * 4 + 3]);
        *reinterpret_cast<float4*>(op + v * 4) = o;
      }
    }
  }
}

extern "C" void kernel_launch(void* const* d_in, const int* in_sizes, int n_in,
                              void* d_out, int out_size, void* d_ws, size_t ws_size,
                              hipStream_t stream) {
  (void)in_sizes; (void)n_in; (void)out_size; (void)ws_size;
  const float* x   = (const float*)d_in[0];
  const float* pos = (const float*)d_in[1];
  const float* W1 = (const float*)d_in[3];
  const float* b1 = (const float*)d_in[4];
  const float* W2 = (const float*)d_in[5];
  const float* b2 = (const float*)d_in[6];
  const float* W3 = (const float*)d_in[7];
  const float* b3 = (const float*)d_in[8];

  float* out     = (float*)d_out;
  float* pos_q   = out + (size_t)NB * NS * NOUT;
  float* batch_q = pos_q + (size_t)NB * NS * 3;

  int* nbr = (int*)d_ws;

  hipLaunchKernelGGL(fps_kernel, dim3(NB), dim3(512), 0, stream,
                     pos, pos_q, batch_q);
  hipLaunchKernelGGL(knn_kernel, dim3(NB * NS), dim3(64), 0, stream,
                     pos, pos_q, nbr);
  hipLaunchKernelGGL(conv_kernel, dim3(NB * NS / QB), dim3(256), 0, stream,
                     x, pos, W1, b1, W2, b2, W3, b3, nbr, pos_q, out);
}

// Round 5
// 1084.196 us; speedup vs baseline: 3.0422x; 1.1823x over previous
//
#include <hip/hip_runtime.h>
#include <math.h>

#define NB   16
#define NP   4096
#define NC   64
#define NS   1024
#define NK   32
#define NH1  64
#define NH2  64
#define NOUT 128
#define NCIN 67

typedef unsigned long long u64;
typedef unsigned int u32;

__device__ inline u64 umin64(u64 a, u64 b) { return a < b ? a : b; }
__device__ inline u64 umax64(u64 a, u64 b) { return a > b ? a : b; }

// round-to-nearest-even f32 -> bf16
__device__ inline unsigned short f2bf(float f) {
  u32 x = __float_as_uint(f);
  return (unsigned short)((x + 0x7fffu + ((x >> 16) & 1u)) >> 16);
}
__device__ inline u32 pack2bf(float a, float b) {
  return (u32)f2bf(a) | ((u32)f2bf(b) << 16);
}
__device__ inline float bf_lo(u32 w) { return __uint_as_float(w << 16); }
__device__ inline float bf_hi(u32 w) { return __uint_as_float(w & 0xffff0000u); }

// ---------------------------------------------------------------------------
// DPP wave64 reductions on packed u64 keys. row_shr 1/2/4/8 accumulates
// toward lane 15 of each 16-lane row; row_bcast15 merges row r -> r+1 (odd
// rows), row_bcast31 merges lane31 -> lanes 32..63. Result lands in lane 63.
// old = own key, bound_ctrl=false -> invalid source lanes keep own value
// (identity for both max and min).
// ---------------------------------------------------------------------------
#define DPP_LVL_MAX(CTRL)                                                     \
  {                                                                           \
    u32 lo = (u32)key, hi = (u32)(key >> 32);                                 \
    u32 plo = (u32)__builtin_amdgcn_update_dpp((int)lo, (int)lo, CTRL, 0xF, 0xF, false); \
    u32 phi = (u32)__builtin_amdgcn_update_dpp((int)hi, (int)hi, CTRL, 0xF, 0xF, false); \
    u64 ok = ((u64)phi << 32) | plo;                                          \
    key = (ok > key) ? ok : key;                                              \
  }
__device__ inline u64 dpp_wavemax_u64(u64 key) {
  DPP_LVL_MAX(0x111) DPP_LVL_MAX(0x112) DPP_LVL_MAX(0x114)
  DPP_LVL_MAX(0x118) DPP_LVL_MAX(0x142) DPP_LVL_MAX(0x143)
  return key;  // lane 63 valid
}
#define DPP_LVL_MIN(CTRL)                                                     \
  {                                                                           \
    u32 lo = (u32)key, hi = (u32)(key >> 32);                                 \
    u32 plo = (u32)__builtin_amdgcn_update_dpp((int)lo, (int)lo, CTRL, 0xF, 0xF, false); \
    u32 phi = (u32)__builtin_amdgcn_update_dpp((int)hi, (int)hi, CTRL, 0xF, 0xF, false); \
    u64 ok = ((u64)phi << 32) | plo;                                          \
    key = (ok < key) ? ok : key;                                              \
  }
__device__ inline u64 dpp_wavemin_bcast_u64(u64 key) {
  DPP_LVL_MIN(0x111) DPP_LVL_MIN(0x112) DPP_LVL_MIN(0x114)
  DPP_LVL_MIN(0x118) DPP_LVL_MIN(0x142) DPP_LVL_MIN(0x143)
  u32 lo = (u32)__builtin_amdgcn_readlane((int)(u32)key, 63);
  u32 hi = (u32)__builtin_amdgcn_readlane((int)(u32)(key >> 32), 63);
  return ((u64)hi << 32) | lo;  // uniform across wave
}

// ---------------------------------------------------------------------------
// FPS: one block per cloud, 256 threads (4 waves, 1/SIMD), 16 pts/thread in
// registers. One barrier per step; DPP reduce (no DS shuffles); lane 63 of
// each wave writes its key; everyone reduces 4 keys. Bit-exact math.
// ---------------------------------------------------------------------------
__global__ __launch_bounds__(256) void fps_kernel(const float* __restrict__ pos,
                                                  float* __restrict__ pos_q,
                                                  float* __restrict__ batch_q) {
  const int b = blockIdx.x;
  const int tid = threadIdx.x;
  const int wave = tid >> 6;
  const float* pb = pos + (size_t)b * NP * 3;

  __shared__ float lx[NP], ly[NP], lz[NP];
  __shared__ u64 s_key[2][4];
  __shared__ int s_idx[NS];

  float px[16], py[16], pz[16], dist[16];
#pragma unroll
  for (int i = 0; i < 16; ++i) {
    int p = i * 256 + tid;
    float xx = pb[p * 3 + 0];
    float yy = pb[p * 3 + 1];
    float zz = pb[p * 3 + 2];
    px[i] = xx; py[i] = yy; pz[i] = zz;
    lx[p] = xx; ly[p] = yy; lz[p] = zz;
    dist[i] = __builtin_inff();
  }
  __syncthreads();

  float fx = lx[0], fy = ly[0], fz = lz[0];
  int far = 0;

  for (int s = 0; s < NS; ++s) {
    if (tid == 0) s_idx[s] = far;

    float bv = -1.0f; int bp = 0;
#pragma unroll
    for (int i = 0; i < 16; ++i) {
      float dx = __fsub_rn(px[i], fx);
      float dy = __fsub_rn(py[i], fy);
      float dz = __fsub_rn(pz[i], fz);
      float d = __fadd_rn(__fadd_rn(__fmul_rn(dx, dx), __fmul_rn(dy, dy)),
                          __fmul_rn(dz, dz));
      d = fminf(dist[i], d);
      dist[i] = d;
      if (d > bv) { bv = d; bp = i * 256 + tid; }
    }

    u64 key = ((u64)__float_as_uint(bv) << 32) | (u32)(NP - 1 - bp);
    key = dpp_wavemax_u64(key);
    if ((tid & 63) == 63) s_key[s & 1][wave] = key;
    __syncthreads();

    u64 k0 = s_key[s & 1][0];
    u64 k1 = s_key[s & 1][1];
    u64 k2 = s_key[s & 1][2];
    u64 k3 = s_key[s & 1][3];
    u64 km = umax64(umax64(k0, k1), umax64(k2, k3));
    far = NP - 1 - (int)(u32)(km & 0xFFFFFFFFull);
    fx = lx[far]; fy = ly[far]; fz = lz[far];
  }
  __syncthreads();

  for (int s = tid; s < NS; s += 256) {
    int p = s_idx[s];
    size_t o = (size_t)(b * NS + s);
    pos_q[o * 3 + 0] = lx[p];
    pos_q[o * 3 + 1] = ly[p];
    pos_q[o * 3 + 2] = lz[p];
    batch_q[o] = (float)b;
  }
}

// ---------------------------------------------------------------------------
// kNN: one wave per query, zero LDS. Per-lane sorted top-4 buffer of packed
// keys; 32 rounds of DPP-min (broadcast via readlane) + owner pop; rare
// refill rescans excluding extracted (per-lane bitmask).
// ---------------------------------------------------------------------------
__global__ __launch_bounds__(64) void knn_kernel(const float* __restrict__ pos,
                                                 const float* __restrict__ pos_q,
                                                 int* __restrict__ nbr) {
  const u64 KMAX = ~0ull;
  const int q = blockIdx.x;
  const int b = q >> 10;
  const int lane = threadIdx.x;
  const float* pb = pos + (size_t)b * NP * 3;
  const float qx = pos_q[q * 3 + 0];
  const float qy = pos_q[q * 3 + 1];
  const float qz = pos_q[q * 3 + 2];

  u64 b0 = KMAX, b1 = KMAX, b2 = KMAX, b3 = KMAX;
#pragma unroll 4
  for (int i = 0; i < 64; ++i) {
    int p = i * 64 + lane;
    float dx = __fsub_rn(pb[p * 3 + 0], qx);
    float dy = __fsub_rn(pb[p * 3 + 1], qy);
    float dz = __fsub_rn(pb[p * 3 + 2], qz);
    float d = __fadd_rn(__fadd_rn(__fmul_rn(dx, dx), __fmul_rn(dy, dy)),
                        __fmul_rn(dz, dz));
    u64 k = ((u64)__float_as_uint(d) << 32) | (u32)p;
    u64 m0 = umax64(b0, k); b0 = umin64(b0, k);
    u64 m1 = umax64(b1, m0); b1 = umin64(b1, m0);
    u64 m2 = umax64(b2, m1); b2 = umin64(b2, m1);
    b3 = umin64(b3, m2);
  }

  u64 exmask = 0ull;
  for (int r = 0; r < NK; ++r) {
    u64 kmin = dpp_wavemin_bcast_u64(b0);
    u32 p = (u32)kmin;
    if (lane == 0) nbr[q * NK + r] = (int)p;
    if ((p & 63u) == (u32)lane) {
      b0 = b1; b1 = b2; b2 = b3; b3 = KMAX;
      exmask |= 1ull << (p >> 6);
      if (b0 == KMAX) {
        for (int i = 0; i < 64; ++i) {
          if ((exmask >> i) & 1ull) continue;
          int pp = i * 64 + lane;
          float dx = __fsub_rn(pb[pp * 3 + 0], qx);
          float dy = __fsub_rn(pb[pp * 3 + 1], qy);
          float dz = __fsub_rn(pb[pp * 3 + 2], qz);
          float d = __fadd_rn(__fadd_rn(__fmul_rn(dx, dx), __fmul_rn(dy, dy)),
                              __fmul_rn(dz, dz));
          u64 k = ((u64)__float_as_uint(d) << 32) | (u32)pp;
          u64 m0 = umax64(b0, k); b0 = umin64(b0, k);
          u64 m1 = umax64(b1, m0); b1 = umin64(b1, m0);
          u64 m2 = umax64(b2, m1); b2 = umin64(b2, m1);
          b3 = umin64(b3, m2);
        }
      }
    }
  }
}

// ---------------------------------------------------------------------------
// PointNetConv: 4 queries/block (one per wave), 256 threads. Activations in
// LDS as bf16 (stride 72 u16); weights streamed from global/L1 with 4 rows x
// 8(16) cols per thread. Max-aggr in registers.
// ---------------------------------------------------------------------------
#define QB 4
#define AST 72

__global__ __launch_bounds__(256) void conv_kernel(
    const float* __restrict__ x, const float* __restrict__ pos,
    const float* __restrict__ W1, const float* __restrict__ b1,
    const float* __restrict__ W2, const float* __restrict__ b2,
    const float* __restrict__ W3, const float* __restrict__ b3,
    const int* __restrict__ nbr, const float* __restrict__ pos_q,
    float* __restrict__ out) {
  __shared__ unsigned short A[QB][32][AST];
  __shared__ unsigned short H[QB][32][AST];
  __shared__ int   s_nbr[QB][32];
  __shared__ float s_qp[QB][3];

  const int tid = threadIdx.x;
  const int wave = tid >> 6;
  const int lane = tid & 63;
  const int q = blockIdx.x * QB + wave;
  const int b = q >> 10;

  if (lane < 32) s_nbr[wave][lane] = nbr[q * NK + lane];
  else if (lane < 35) s_qp[wave][lane - 32] = pos_q[q * 3 + (lane - 32)];
  __syncthreads();

  {
    const int row = lane >> 1, half = lane & 1;
    const float* src = x + ((size_t)b * NP + s_nbr[wave][row]) * NC + half * 32;
    unsigned short* dst = &A[wave][row][half * 32];
#pragma unroll
    for (int t = 0; t < 8; ++t) {
      float4 v = reinterpret_cast<const float4*>(src)[t];
      u32 lo = pack2bf(v.x, v.y);
      u32 hi = pack2bf(v.z, v.w);
      *reinterpret_cast<uint2*>(dst + t * 4) = make_uint2(lo, hi);
    }
  }
  if (lane < 32) {
    const float* pp = pos + ((size_t)b * NP + s_nbr[wave][lane]) * 3;
    float rx = __fsub_rn(pp[0], s_qp[wave][0]);
    float ry = __fsub_rn(pp[1], s_qp[wave][1]);
    float rz = __fsub_rn(pp[2], s_qp[wave][2]);
    u32* dw = reinterpret_cast<u32*>(&A[wave][lane][64]);
    dw[0] = pack2bf(rx, ry);
    dw[1] = pack2bf(rz, 0.0f);
  }
  __syncthreads();

  const int rg = (lane >> 3) & 7;
  const int cg = lane & 7;

  float acc[4][8];

  // ----- layer 1 -----
  {
    float4 bb0 = *reinterpret_cast<const float4*>(&b1[cg * 8]);
    float4 bb1 = *reinterpret_cast<const float4*>(&b1[cg * 8 + 4]);
#pragma unroll
    for (int u = 0; u < 4; ++u) {
      acc[u][0] = bb0.x; acc[u][1] = bb0.y; acc[u][2] = bb0.z; acc[u][3] = bb0.w;
      acc[u][4] = bb1.x; acc[u][5] = bb1.y; acc[u][6] = bb1.z; acc[u][7] = bb1.w;
    }
    for (int jb = 0; jb < 8; ++jb) {
      uint4 ar[4];
#pragma unroll
      for (int u = 0; u < 4; ++u)
        ar[u] = *reinterpret_cast<const uint4*>(&A[wave][rg + 8 * u][jb * 8]);
#pragma unroll
      for (int jj = 0; jj < 8; ++jj) {
        int j = jb * 8 + jj;
        float4 w0 = *reinterpret_cast<const float4*>(&W1[j * NH1 + cg * 8]);
        float4 w1 = *reinterpret_cast<const float4*>(&W1[j * NH1 + cg * 8 + 4]);
        float av[4];
#pragma unroll
        for (int u = 0; u < 4; ++u) {
          u32 word = reinterpret_cast<const u32*>(&ar[u])[jj >> 1];
          av[u] = (jj & 1) ? bf_hi(word) : bf_lo(word);
        }
#pragma unroll
        for (int u = 0; u < 4; ++u) {
          acc[u][0] = fmaf(av[u], w0.x, acc[u][0]);
          acc[u][1] = fmaf(av[u], w0.y, acc[u][1]);
          acc[u][2] = fmaf(av[u], w0.z, acc[u][2]);
          acc[u][3] = fmaf(av[u], w0.w, acc[u][3]);
          acc[u][4] = fmaf(av[u], w1.x, acc[u][4]);
          acc[u][5] = fmaf(av[u], w1.y, acc[u][5]);
          acc[u][6] = fmaf(av[u], w1.z, acc[u][6]);
          acc[u][7] = fmaf(av[u], w1.w, acc[u][7]);
        }
      }
    }
    uint2 tw[4];
#pragma unroll
    for (int u = 0; u < 4; ++u)
      tw[u] = *reinterpret_cast<const uint2*>(&A[wave][rg + 8 * u][64]);
#pragma unroll
    for (int jj = 0; jj < 3; ++jj) {
      int j = 64 + jj;
      float4 w0 = *reinterpret_cast<const float4*>(&W1[j * NH1 + cg * 8]);
      float4 w1 = *reinterpret_cast<const float4*>(&W1[j * NH1 + cg * 8 + 4]);
      float av[4];
#pragma unroll
      for (int u = 0; u < 4; ++u)
        av[u] = (jj == 0) ? bf_lo(tw[u].x) : (jj == 1) ? bf_hi(tw[u].x) : bf_lo(tw[u].y);
#pragma unroll
      for (int u = 0; u < 4; ++u) {
        acc[u][0] = fmaf(av[u], w0.x, acc[u][0]);
        acc[u][1] = fmaf(av[u], w0.y, acc[u][1]);
        acc[u][2] = fmaf(av[u], w0.z, acc[u][2]);
        acc[u][3] = fmaf(av[u], w0.w, acc[u][3]);
        acc[u][4] = fmaf(av[u], w1.x, acc[u][4]);
        acc[u][5] = fmaf(av[u], w1.y, acc[u][5]);
        acc[u][6] = fmaf(av[u], w1.z, acc[u][6]);
        acc[u][7] = fmaf(av[u], w1.w, acc[u][7]);
      }
    }
#pragma unroll
    for (int u = 0; u < 4; ++u) {
      uint4 hw;
      hw.x = pack2bf(fmaxf(acc[u][0], 0.f), fmaxf(acc[u][1], 0.f));
      hw.y = pack2bf(fmaxf(acc[u][2], 0.f), fmaxf(acc[u][3], 0.f));
      hw.z = pack2bf(fmaxf(acc[u][4], 0.f), fmaxf(acc[u][5], 0.f));
      hw.w = pack2bf(fmaxf(acc[u][6], 0.f), fmaxf(acc[u][7], 0.f));
      *reinterpret_cast<uint4*>(&H[wave][rg + 8 * u][cg * 8]) = hw;
    }
  }
  __syncthreads();

  // ----- layer 2 -----
  {
    float4 bb0 = *reinterpret_cast<const float4*>(&b2[cg * 8]);
    float4 bb1 = *reinterpret_cast<const float4*>(&b2[cg * 8 + 4]);
#pragma unroll
    for (int u = 0; u < 4; ++u) {
      acc[u][0] = bb0.x; acc[u][1] = bb0.y; acc[u][2] = bb0.z; acc[u][3] = bb0.w;
      acc[u][4] = bb1.x; acc[u][5] = bb1.y; acc[u][6] = bb1.z; acc[u][7] = bb1.w;
    }
    for (int jb = 0; jb < 8; ++jb) {
      uint4 ar[4];
#pragma unroll
      for (int u = 0; u < 4; ++u)
        ar[u] = *reinterpret_cast<const uint4*>(&H[wave][rg + 8 * u][jb * 8]);
#pragma unroll
      for (int jj = 0; jj < 8; ++jj) {
        int j = jb * 8 + jj;
        float4 w0 = *reinterpret_cast<const float4*>(&W2[j * NH2 + cg * 8]);
        float4 w1 = *reinterpret_cast<const float4*>(&W2[j * NH2 + cg * 8 + 4]);
        float av[4];
#pragma unroll
        for (int u = 0; u < 4; ++u) {
          u32 word = reinterpret_cast<const u32*>(&ar[u])[jj >> 1];
          av[u] = (jj & 1) ? bf_hi(word) : bf_lo(word);
        }
#pragma unroll
        for (int u = 0; u < 4; ++u) {
          acc[u][0] = fmaf(av[u], w0.x, acc[u][0]);
          acc[u][1] = fmaf(av[u], w0.y, acc[u][1]);
          acc[u][2] = fmaf(av[u], w0.z, acc[u][2]);
          acc[u][3] = fmaf(av[u], w0.w, acc[u][3]);
          acc[u][4] = fmaf(av[u], w1.x, acc[u][4]);
          acc[u][5] = fmaf(av[u], w1.y, acc[u][5]);
          acc[u][6] = fmaf(av[u], w1.z, acc[u][6]);
          acc[u][7] = fmaf(av[u], w1.w, acc[u][7]);
        }
      }
    }
#pragma unroll
    for (int u = 0; u < 4; ++u) {
      uint4 hw;
      hw.x = pack2bf(fmaxf(acc[u][0], 0.f), fmaxf(acc[u][1], 0.f));
      hw.y = pack2bf(fmaxf(acc[u][2], 0.f), fmaxf(acc[u][3], 0.f));
      hw.z = pack2bf(fmaxf(acc[u][4], 0.f), fmaxf(acc[u][5], 0.f));
      hw.w = pack2bf(fmaxf(acc[u][6], 0.f), fmaxf(acc[u][7], 0.f));
      *reinterpret_cast<uint4*>(&A[wave][rg + 8 * u][cg * 8]) = hw;
    }
  }
  __syncthreads();

  // ----- layer 3 + max -----
  {
    float a3[4][16];
#pragma unroll
    for (int v = 0; v < 4; ++v) {
      float4 bb = *reinterpret_cast<const float4*>(&b3[cg * 16 + v * 4]);
#pragma unroll
      for (int u = 0; u < 4; ++u) {
        a3[u][v * 4 + 0] = bb.x; a3[u][v * 4 + 1] = bb.y;
        a3[u][v * 4 + 2] = bb.z; a3[u][v * 4 + 3] = bb.w;
      }
    }
    for (int jb = 0; jb < 8; ++jb) {
      uint4 ar[4];
#pragma unroll
      for (int u = 0; u < 4; ++u)
        ar[u] = *reinterpret_cast<const uint4*>(&A[wave][rg + 8 * u][jb * 8]);
#pragma unroll
      for (int jj = 0; jj < 8; ++jj) {
        int j = jb * 8 + jj;
        float av[4];
#pragma unroll
        for (int u = 0; u < 4; ++u) {
          u32 word = reinterpret_cast<const u32*>(&ar[u])[jj >> 1];
          av[u] = (jj & 1) ? bf_hi(word) : bf_lo(word);
        }
#pragma unroll
        for (int v = 0; v < 4; ++v) {
          float4 w = *reinterpret_cast<const float4*>(&W3[j * NOUT + cg * 16 + v * 4]);
#pragma unroll
          for (int u = 0; u < 4; ++u) {
            a3[u][v * 4 + 0] = fmaf(av[u], w.x, a3[u][v * 4 + 0]);
            a3[u][v * 4 + 1] = fmaf(av[u], w.y, a3[u][v * 4 + 1]);
            a3[u][v * 4 + 2] = fmaf(av[u], w.z, a3[u][v * 4 + 2]);
            a3[u][v * 4 + 3] = fmaf(av[u], w.w, a3[u][v * 4 + 3]);
          }
        }
      }
    }
    float m[16];
#pragma unroll
    for (int t = 0; t < 16; ++t)
      m[t] = fmaxf(fmaxf(a3[0][t], a3[1][t]), fmaxf(a3[2][t], a3[3][t]));
#pragma unroll
    for (int off = 8; off < 64; off <<= 1) {
#pragma unroll
      for (int t = 0; t < 16; ++t)
        m[t] = fmaxf(m[t], __shfl_xor(m[t], off, 64));
    }
    if (rg == 0) {
      float* op = out + (size_t)q * NOUT + cg * 16;
#pragma unroll
      for (int v = 0; v < 4; ++v) {
        float4 o = make_float4(m[v * 4 + 0], m[v * 4 + 1], m[v * 4 + 2], m[v * 4 + 3]);
        *reinterpret_cast<float4*>(op + v * 4) = o;
      }
    }
  }
}

extern "C" void kernel_launch(void* const* d_in, const int* in_sizes, int n_in,
                              void* d_out, int out_size, void* d_ws, size_t ws_size,
                              hipStream_t stream) {
  (void)in_sizes; (void)n_in; (void)out_size; (void)ws_size;
  const float* x   = (const float*)d_in[0];
  const float* pos = (const float*)d_in[1];
  const float* W1 = (const float*)d_in[3];
  const float* b1 = (const float*)d_in[4];
  const float* W2 = (const float*)d_in[5];
  const float* b2 = (const float*)d_in[6];
  const float* W3 = (const float*)d_in[7];
  const float* b3 = (const float*)d_in[8];

  float* out     = (float*)d_out;
  float* pos_q   = out + (size_t)NB * NS * NOUT;
  float* batch_q = pos_q + (size_t)NB * NS * 3;

  int* nbr = (int*)d_ws;

  hipLaunchKernelGGL(fps_kernel, dim3(NB), dim3(256), 0, stream,
                     pos, pos_q, batch_q);
  hipLaunchKernelGGL(knn_kernel, dim3(NB * NS), dim3(64), 0, stream,
                     pos, pos_q, nbr);
  hipLaunchKernelGGL(conv_kernel, dim3(NB * NS / QB), dim3(256), 0, stream,
                     x, pos, W1, b1, W2, b2, W3, b3, nbr, pos_q, out);
}

// Round 7
// 781.059 us; speedup vs baseline: 4.2229x; 1.3881x over previous
//
#include <hip/hip_runtime.h>
#include <math.h>
#include <string.h>

#define NB   16
#define NP   4096
#define NC   64
#define NS   1024
#define NK   32
#define NH1  64
#define NH2  64
#define NOUT 128

typedef unsigned long long u64;
typedef unsigned int u32;
typedef unsigned short u16;
typedef __attribute__((ext_vector_type(8))) short s16x8;
typedef __attribute__((ext_vector_type(4))) float f32x4;

__device__ inline u64 umin64(u64 a, u64 b) { return a < b ? a : b; }
__device__ inline u64 umax64(u64 a, u64 b) { return a > b ? a : b; }

// round-to-nearest-even f32 -> bf16
__device__ inline u16 f2bf(float f) {
  u32 x = __float_as_uint(f);
  return (u16)((x + 0x7fffu + ((x >> 16) & 1u)) >> 16);
}
__device__ inline u32 pack2bf(float a, float b) {
  return (u32)f2bf(a) | ((u32)f2bf(b) << 16);
}

__device__ inline float d2exact(float ax, float ay, float az,
                                float qx, float qy, float qz) {
  float dx = __fsub_rn(ax, qx), dy = __fsub_rn(ay, qy), dz = __fsub_rn(az, qz);
  return __fadd_rn(__fadd_rn(__fmul_rn(dx, dx), __fmul_rn(dy, dy)),
                   __fmul_rn(dz, dz));
}

// ---------------------------------------------------------------------------
// DPP wave64 reductions on packed u64 keys (row_shr toward lane15, bcast15,
// bcast31 -> result in lane 63). Verified in round 5.
// ---------------------------------------------------------------------------
#define DPP_LVL_MAX(CTRL)                                                     \
  {                                                                           \
    u32 lo = (u32)key, hi = (u32)(key >> 32);                                 \
    u32 plo = (u32)__builtin_amdgcn_update_dpp((int)lo, (int)lo, CTRL, 0xF, 0xF, false); \
    u32 phi = (u32)__builtin_amdgcn_update_dpp((int)hi, (int)hi, CTRL, 0xF, 0xF, false); \
    u64 ok = ((u64)phi << 32) | plo;                                          \
    key = (ok > key) ? ok : key;                                              \
  }
__device__ inline u64 dpp_wavemax_u64(u64 key) {
  DPP_LVL_MAX(0x111) DPP_LVL_MAX(0x112) DPP_LVL_MAX(0x114)
  DPP_LVL_MAX(0x118) DPP_LVL_MAX(0x142) DPP_LVL_MAX(0x143)
  return key;  // lane 63 valid
}
#define DPP_LVL_MIN(CTRL)                                                     \
  {                                                                           \
    u32 lo = (u32)key, hi = (u32)(key >> 32);                                 \
    u32 plo = (u32)__builtin_amdgcn_update_dpp((int)lo, (int)lo, CTRL, 0xF, 0xF, false); \
    u32 phi = (u32)__builtin_amdgcn_update_dpp((int)hi, (int)hi, CTRL, 0xF, 0xF, false); \
    u64 ok = ((u64)phi << 32) | plo;                                          \
    key = (ok < key) ? ok : key;                                              \
  }
__device__ inline u64 dpp_wavemin_bcast_u64(u64 key) {
  DPP_LVL_MIN(0x111) DPP_LVL_MIN(0x112) DPP_LVL_MIN(0x114)
  DPP_LVL_MIN(0x118) DPP_LVL_MIN(0x142) DPP_LVL_MIN(0x143)
  u32 lo = (u32)__builtin_amdgcn_readlane((int)(u32)key, 63);
  u32 hi = (u32)__builtin_amdgcn_readlane((int)(u32)(key >> 32), 63);
  return ((u64)hi << 32) | lo;  // uniform across wave
}

// fmax with DPP neighbor, literal ctrl (16-lane-row reduction for conv max)
#define DPP_FMAX_STAGE(CTRL)                                                  \
  do {                                                                        \
    _Pragma("unroll")                                                         \
    for (int mt = 0; mt < 8; ++mt) {                                          \
      _Pragma("unroll")                                                       \
      for (int r = 0; r < 4; ++r) {                                           \
        int vi = __float_as_int(m[mt][r]);                                    \
        int ov = __builtin_amdgcn_update_dpp(vi, vi, CTRL, 0xF, 0xF, false);  \
        m[mt][r] = fmaxf(m[mt][r], __int_as_float(ov));                       \
      }                                                                       \
    }                                                                         \
  } while (0)

// ---------------------------------------------------------------------------
// FPS (unchanged from round 5, passing @ ~607us)
// ---------------------------------------------------------------------------
__global__ __launch_bounds__(256) void fps_kernel(const float* __restrict__ pos,
                                                  float* __restrict__ pos_q,
                                                  float* __restrict__ batch_q) {
  const int b = blockIdx.x;
  const int tid = threadIdx.x;
  const int wave = tid >> 6;
  const float* pb = pos + (size_t)b * NP * 3;

  __shared__ float lx[NP], ly[NP], lz[NP];
  __shared__ u64 s_key[2][4];
  __shared__ int s_idx[NS];

  float px[16], py[16], pz[16], dist[16];
#pragma unroll
  for (int i = 0; i < 16; ++i) {
    int p = i * 256 + tid;
    float xx = pb[p * 3 + 0];
    float yy = pb[p * 3 + 1];
    float zz = pb[p * 3 + 2];
    px[i] = xx; py[i] = yy; pz[i] = zz;
    lx[p] = xx; ly[p] = yy; lz[p] = zz;
    dist[i] = __builtin_inff();
  }
  __syncthreads();

  float fx = lx[0], fy = ly[0], fz = lz[0];
  int far = 0;

  for (int s = 0; s < NS; ++s) {
    if (tid == 0) s_idx[s] = far;

    float bv = -1.0f; int bp = 0;
#pragma unroll
    for (int i = 0; i < 16; ++i) {
      float dx = __fsub_rn(px[i], fx);
      float dy = __fsub_rn(py[i], fy);
      float dz = __fsub_rn(pz[i], fz);
      float d = __fadd_rn(__fadd_rn(__fmul_rn(dx, dx), __fmul_rn(dy, dy)),
                          __fmul_rn(dz, dz));
      d = fminf(dist[i], d);
      dist[i] = d;
      if (d > bv) { bv = d; bp = i * 256 + tid; }
    }

    u64 key = ((u64)__float_as_uint(bv) << 32) | (u32)(NP - 1 - bp);
    key = dpp_wavemax_u64(key);
    if ((tid & 63) == 63) s_key[s & 1][wave] = key;
    __syncthreads();

    u64 k0 = s_key[s & 1][0];
    u64 k1 = s_key[s & 1][1];
    u64 k2 = s_key[s & 1][2];
    u64 k3 = s_key[s & 1][3];
    u64 km = umax64(umax64(k0, k1), umax64(k2, k3));
    far = NP - 1 - (int)(u32)(km & 0xFFFFFFFFull);
    fx = lx[far]; fy = ly[far]; fz = lz[far];
  }
  __syncthreads();

  for (int s = tid; s < NS; s += 256) {
    int p = s_idx[s];
    size_t o = (size_t)(b * NS + s);
    pos_q[o * 3 + 0] = lx[p];
    pos_q[o * 3 + 1] = ly[p];
    pos_q[o * 3 + 2] = lz[p];
    batch_q[o] = (float)b;
  }
}

// ---------------------------------------------------------------------------
// kNN: one wave per query. Initial scan: 4 points/lane via 3x float4 (48 B
// contiguous per lane, coalesced). Sorted top-4 buffer of packed keys;
// 32 rounds DPP-min + owner pop; rare refill rescans non-extracted slots.
// Owner of point p: lane (p>>2)&63; slot = (p>>8)*4 + (p&3).
// ---------------------------------------------------------------------------
__device__ inline void ins4(u64& b0, u64& b1, u64& b2, u64& b3, u64 k) {
  u64 m0 = umax64(b0, k); b0 = umin64(b0, k);
  u64 m1 = umax64(b1, m0); b1 = umin64(b1, m0);
  u64 m2 = umax64(b2, m1); b2 = umin64(b2, m1);
  b3 = umin64(b3, m2);
}

__global__ __launch_bounds__(64) void knn_kernel(const float* __restrict__ pos,
                                                 const float* __restrict__ pos_q,
                                                 int* __restrict__ nbr) {
  const u64 KMAX = ~0ull;
  const int q = blockIdx.x;
  const int b = q >> 10;
  const int lane = threadIdx.x;
  const float* pb = pos + (size_t)b * NP * 3;
  const float qx = pos_q[q * 3 + 0];
  const float qy = pos_q[q * 3 + 1];
  const float qz = pos_q[q * 3 + 2];

  u64 b0 = KMAX, b1 = KMAX, b2 = KMAX, b3 = KMAX;
#pragma unroll 4
  for (int gg = 0; gg < 16; ++gg) {
    int p = gg * 256 + lane * 4;
    const float* s = pb + (size_t)p * 3;
    float4 v0 = *(const float4*)(s);
    float4 v1 = *(const float4*)(s + 4);
    float4 v2 = *(const float4*)(s + 8);
    float d0 = d2exact(v0.x, v0.y, v0.z, qx, qy, qz);
    float d1 = d2exact(v0.w, v1.x, v1.y, qx, qy, qz);
    float d2 = d2exact(v1.z, v1.w, v2.x, qx, qy, qz);
    float d3 = d2exact(v2.y, v2.z, v2.w, qx, qy, qz);
    ins4(b0, b1, b2, b3, ((u64)__float_as_uint(d0) << 32) | (u32)(p + 0));
    ins4(b0, b1, b2, b3, ((u64)__float_as_uint(d1) << 32) | (u32)(p + 1));
    ins4(b0, b1, b2, b3, ((u64)__float_as_uint(d2) << 32) | (u32)(p + 2));
    ins4(b0, b1, b2, b3, ((u64)__float_as_uint(d3) << 32) | (u32)(p + 3));
  }

  u64 exmask = 0ull;
  for (int r = 0; r < NK; ++r) {
    u64 kmin = dpp_wavemin_bcast_u64(b0);
    u32 p = (u32)kmin;
    if (lane == 0) nbr[q * NK + r] = (int)p;
    if (((p >> 2) & 63u) == (u32)lane) {
      b0 = b1; b1 = b2; b2 = b3; b3 = KMAX;
      exmask |= 1ull << (((p >> 8) << 2) | (p & 3u));
      if (b0 == KMAX) {
        for (int gg = 0; gg < 16; ++gg) {
          int pp = gg * 256 + lane * 4;
          const float* s = pb + (size_t)pp * 3;
          float4 v0 = *(const float4*)(s);
          float4 v1 = *(const float4*)(s + 4);
          float4 v2 = *(const float4*)(s + 8);
          float dd[4];
          dd[0] = d2exact(v0.x, v0.y, v0.z, qx, qy, qz);
          dd[1] = d2exact(v0.w, v1.x, v1.y, qx, qy, qz);
          dd[2] = d2exact(v1.z, v1.w, v2.x, qx, qy, qz);
          dd[3] = d2exact(v2.y, v2.z, v2.w, qx, qy, qz);
#pragma unroll
          for (int rr = 0; rr < 4; ++rr) {
            int slot = gg * 4 + rr;
            if ((exmask >> slot) & 1ull) continue;
            ins4(b0, b1, b2, b3,
                 ((u64)__float_as_uint(dd[rr]) << 32) | (u32)(pp + rr));
          }
        }
      }
    }
  }
}

// ---------------------------------------------------------------------------
// Weight prepack: convert W1/W2/W3 (f32) into bf16 MFMA A-fragments
// (transposed convention: A = W^T, M = out-channels). Fragment element
// (layer, mt, kc, lane, j) holds W[k = kc*32 + 8*(lane>>4) + j][mt*16 +
// (lane&15)], zero-padded past the layer's K. One 16-B load per frag in conv.
// ---------------------------------------------------------------------------
#define WF_L2 6144
#define WF_L3 10240
#define WF_TOT 18432

__global__ __launch_bounds__(256) void prep_kernel(
    const float* __restrict__ W1, const float* __restrict__ W2,
    const float* __restrict__ W3, u16* __restrict__ wf) {
  int flat = blockIdx.x * 256 + threadIdx.x;
  if (flat >= WF_TOT) return;
  float val;
  int j = flat & 7, lane = (flat >> 3) & 63, t = flat >> 9;
  int k8 = 8 * (lane >> 4) + j, li = lane & 15;
  if (flat < WF_L2) {
    int kc = t % 3, mt = t / 3;                 // mt<4, kc<3, K=96 (Kact=67)
    int k = kc * 32 + k8;
    val = (k < 67) ? W1[k * 64 + mt * 16 + li] : 0.0f;
  } else if (flat < WF_L3) {
    t -= WF_L2 >> 9;
    int kc = t & 1, mt = t >> 1;                // mt<4, kc<2, K=64
    val = W2[(kc * 32 + k8) * 64 + mt * 16 + li];
  } else {
    t -= WF_L3 >> 9;
    int kc = t & 1, mt = t >> 1;                // mt<8, kc<2, K=64
    val = W3[(kc * 32 + k8) * 128 + mt * 16 + li];
  }
  wf[flat] = f2bf(val);
}

// ---------------------------------------------------------------------------
// PointNetConv via MFMA 16x16x32 bf16, transposed convention:
//   H^T[ch][nbr] = (W^T)[ch][k] * (act^T)[k][nbr]
// One query per wave, 4 waves/block, no block barriers (wave-private LDS
// bounce between layers). D-frag: col=lane&15 (nbr), row=(lane>>4)*4+reg (ch).
// B-frag: col=lane&15 (nbr), k = 8*(lane>>4)+j. A-frags prepacked in wf.
// ---------------------------------------------------------------------------
#define HST 72  // u16 stride of H rows (144 B, 16B-multiple)

__global__ __launch_bounds__(256) void conv_kernel(
    const float* __restrict__ x, const float* __restrict__ pos,
    const u16* __restrict__ wf,
    const float* __restrict__ b1, const float* __restrict__ b2,
    const float* __restrict__ b3,
    const int* __restrict__ nbr, const float* __restrict__ pos_q,
    float* __restrict__ out) {
  __shared__ u16 Hs[4][32][HST];

  const int tid = threadIdx.x, wave = tid >> 6, lane = tid & 63;
  const int q = blockIdx.x * 4 + wave;
  const int b = q >> 10;
  const int g = lane >> 4, li = lane & 15;

  const int n0 = nbr[q * NK + li];
  const int n1 = nbr[q * NK + li + 16];
  const float qx = pos_q[q * 3 + 0];
  const float qy = pos_q[q * 3 + 1];
  const float qz = pos_q[q * 3 + 2];

  // ---- gather B1 fragments (activations^T) ----
  uint4 bf1[2][3];
  {
    const float* xb = x + (size_t)b * NP * NC;
#pragma unroll
    for (int nt = 0; nt < 2; ++nt) {
      const float* s = xb + (size_t)(nt ? n1 : n0) * NC + 8 * g;
#pragma unroll
      for (int kc = 0; kc < 2; ++kc) {
        float4 v0 = *(const float4*)(s + kc * 32);
        float4 v1 = *(const float4*)(s + kc * 32 + 4);
        bf1[nt][kc] = make_uint4(pack2bf(v0.x, v0.y), pack2bf(v0.z, v0.w),
                                 pack2bf(v1.x, v1.y), pack2bf(v1.z, v1.w));
      }
      const float* pp = pos + ((size_t)b * NP + (nt ? n1 : n0)) * 3;
      float rx = __fsub_rn(pp[0], qx);
      float ry = __fsub_rn(pp[1], qy);
      float rz = __fsub_rn(pp[2], qz);
      uint4 w = make_uint4(0u, 0u, 0u, 0u);
      if (g == 0) { w.x = pack2bf(rx, ry); w.y = pack2bf(rz, 0.0f); }
      bf1[nt][2] = w;
    }
  }

  const uint4* wf4 = (const uint4*)wf;

  // ---- layer 1: M=64 (4 mt), K=96 (3 kc), N=32 (2 nt), relu ----
  {
    f32x4 acc[4][2];
#pragma unroll
    for (int mt = 0; mt < 4; ++mt) {
      float4 bb = *(const float4*)(b1 + mt * 16 + 4 * g);
      acc[mt][0] = f32x4{bb.x, bb.y, bb.z, bb.w};
      acc[mt][1] = acc[mt][0];
    }
#pragma unroll
    for (int mt = 0; mt < 4; ++mt)
#pragma unroll
      for (int kc = 0; kc < 3; ++kc) {
        uint4 aw = wf4[(mt * 3 + kc) * 64 + lane];
        s16x8 a = __builtin_bit_cast(s16x8, aw);
        acc[mt][0] = __builtin_amdgcn_mfma_f32_16x16x32_bf16(
            a, __builtin_bit_cast(s16x8, bf1[0][kc]), acc[mt][0], 0, 0, 0);
        acc[mt][1] = __builtin_amdgcn_mfma_f32_16x16x32_bf16(
            a, __builtin_bit_cast(s16x8, bf1[1][kc]), acc[mt][1], 0, 0, 0);
      }
    // relu + bf16 -> Hs[nbr][ch]
#pragma unroll
    for (int mt = 0; mt < 4; ++mt)
#pragma unroll
      for (int nt = 0; nt < 2; ++nt) {
        f32x4 v = acc[mt][nt];
        u32 w0 = pack2bf(fmaxf(v[0], 0.f), fmaxf(v[1], 0.f));
        u32 w1 = pack2bf(fmaxf(v[2], 0.f), fmaxf(v[3], 0.f));
        *(uint2*)&Hs[wave][li + 16 * nt][mt * 16 + 4 * g] = make_uint2(w0, w1);
      }
  }
  asm volatile("s_waitcnt lgkmcnt(0)" ::: "memory");

  // ---- layer 2: M=64 (4 mt), K=64 (2 kc), N=32, relu ----
  {
    uint4 bf2[2][2];
#pragma unroll
    for (int nt = 0; nt < 2; ++nt)
#pragma unroll
      for (int kc = 0; kc < 2; ++kc)
        bf2[nt][kc] = *(const uint4*)&Hs[wave][li + 16 * nt][kc * 32 + 8 * g];

    f32x4 acc[4][2];
#pragma unroll
    for (int mt = 0; mt < 4; ++mt) {
      float4 bb = *(const float4*)(b2 + mt * 16 + 4 * g);
      acc[mt][0] = f32x4{bb.x, bb.y, bb.z, bb.w};
      acc[mt][1] = acc[mt][0];
    }
#pragma unroll
    for (int mt = 0; mt < 4; ++mt)
#pragma unroll
      for (int kc = 0; kc < 2; ++kc) {
        uint4 aw = wf4[(WF_L2 >> 3) + (mt * 2 + kc) * 64 + lane];
        s16x8 a = __builtin_bit_cast(s16x8, aw);
        acc[mt][0] = __builtin_amdgcn_mfma_f32_16x16x32_bf16(
            a, __builtin_bit_cast(s16x8, bf2[0][kc]), acc[mt][0], 0, 0, 0);
        acc[mt][1] = __builtin_amdgcn_mfma_f32_16x16x32_bf16(
            a, __builtin_bit_cast(s16x8, bf2[1][kc]), acc[mt][1], 0, 0, 0);
      }
#pragma unroll
    for (int mt = 0; mt < 4; ++mt)
#pragma unroll
      for (int nt = 0; nt < 2; ++nt) {
        f32x4 v = acc[mt][nt];
        u32 w0 = pack2bf(fmaxf(v[0], 0.f), fmaxf(v[1], 0.f));
        u32 w1 = pack2bf(fmaxf(v[2], 0.f), fmaxf(v[3], 0.f));
        *(uint2*)&Hs[wave][li + 16 * nt][mt * 16 + 4 * g] = make_uint2(w0, w1);
      }
  }
  asm volatile("s_waitcnt lgkmcnt(0)" ::: "memory");

  // ---- layer 3: M=128 (8 mt), K=64 (2 kc), N=32, plain; then max over nbr --
  {
    uint4 bf3[2][2];
#pragma unroll
    for (int nt = 0; nt < 2; ++nt)
#pragma unroll
      for (int kc = 0; kc < 2; ++kc)
        bf3[nt][kc] = *(const uint4*)&Hs[wave][li + 16 * nt][kc * 32 + 8 * g];

    f32x4 acc[8][2];
#pragma unroll
    for (int mt = 0; mt < 8; ++mt) {
      float4 bb = *(const float4*)(b3 + mt * 16 + 4 * g);
      acc[mt][0] = f32x4{bb.x, bb.y, bb.z, bb.w};
      acc[mt][1] = acc[mt][0];
    }
#pragma unroll
    for (int mt = 0; mt < 8; ++mt)
#pragma unroll
      for (int kc = 0; kc < 2; ++kc) {
        uint4 aw = wf4[(WF_L3 >> 3) + (mt * 2 + kc) * 64 + lane];
        s16x8 a = __builtin_bit_cast(s16x8, aw);
        acc[mt][0] = __builtin_amdgcn_mfma_f32_16x16x32_bf16(
            a, __builtin_bit_cast(s16x8, bf3[0][kc]), acc[mt][0], 0, 0, 0);
        acc[mt][1] = __builtin_amdgcn_mfma_f32_16x16x32_bf16(
            a, __builtin_bit_cast(s16x8, bf3[1][kc]), acc[mt][1], 0, 0, 0);
      }

    // max over neighbors: fold nt, then 4-stage DPP reduce within 16-lane row
    float m[8][4];
#pragma unroll
    for (int mt = 0; mt < 8; ++mt)
#pragma unroll
      for (int r = 0; r < 4; ++r)
        m[mt][r] = fmaxf(acc[mt][0][r], acc[mt][1][r]);

    DPP_FMAX_STAGE(0xB1);   // quad_perm xor1
    DPP_FMAX_STAGE(0x4E);   // quad_perm xor2
    DPP_FMAX_STAGE(0x141);  // row_half_mirror (xor4)
    DPP_FMAX_STAGE(0x140);  // row_mirror (xor8)

    // writers: lane with li == mt stores float4 at ch = mt*16 + 4g
#pragma unroll
    for (int mt = 0; mt < 8; ++mt) {
      if (li == mt) {
        float4 o = make_float4(m[mt][0], m[mt][1], m[mt][2], m[mt][3]);
        *(float4*)(out + (size_t)q * NOUT + mt * 16 + 4 * g) = o;
      }
    }
  }
}

extern "C" void kernel_launch(void* const* d_in, const int* in_sizes, int n_in,
                              void* d_out, int out_size, void* d_ws, size_t ws_size,
                              hipStream_t stream) {
  (void)in_sizes; (void)n_in; (void)out_size; (void)ws_size;
  const float* x   = (const float*)d_in[0];
  const float* pos = (const float*)d_in[1];
  const float* W1 = (const float*)d_in[3];
  const float* b1 = (const float*)d_in[4];
  const float* W2 = (const float*)d_in[5];
  const float* b2 = (const float*)d_in[6];
  const float* W3 = (const float*)d_in[7];
  const float* b3 = (const float*)d_in[8];

  float* out     = (float*)d_out;
  float* pos_q   = out + (size_t)NB * NS * NOUT;
  float* batch_q = pos_q + (size_t)NB * NS * 3;

  int* nbr = (int*)d_ws;                                   // 2 MB
  u16* wfrag = (u16*)((char*)d_ws + (size_t)NB * NS * NK * 4);  // 36 KB

  hipLaunchKernelGGL(prep_kernel, dim3((WF_TOT + 255) / 256), dim3(256), 0,
                     stream, W1, W2, W3, wfrag);
  hipLaunchKernelGGL(fps_kernel, dim3(NB), dim3(256), 0, stream,
                     pos, pos_q, batch_q);
  hipLaunchKernelGGL(knn_kernel, dim3(NB * NS), dim3(64), 0, stream,
                     pos, pos_q, nbr);
  hipLaunchKernelGGL(conv_kernel, dim3(NB * NS / 4), dim3(256), 0, stream,
                     x, pos, wfrag, b1, b2, b3, nbr, pos_q, out);
}